// Round 1
// baseline (226.937 us; speedup 1.0000x reference)
//
#include <hip/hip_runtime.h>

#define B_ 16
#define C_ 306
#define T_ 4000
#define M_ 128

// ---------------- Kernel A: gate MLP -> w[b][c][m] (unnormalized) -------------
__global__ void gate_kernel(const float* __restrict__ positions,   // [B,C,2]
                            const float* __restrict__ target,      // [M,2]
                            const float* __restrict__ w1,          // [3,32]
                            const float* __restrict__ b1,          // [32]
                            const float* __restrict__ w2,          // [32]
                            const float* __restrict__ b2,          // [1]
                            float* __restrict__ wout) {            // [B,C,M]
    __shared__ float s_w1[96], s_b1[32], s_w2[32], s_b2;
    const int tid = threadIdx.x;
    if (tid < 96) s_w1[tid] = w1[tid];
    if (tid < 32) { s_b1[tid] = b1[tid]; s_w2[tid] = w2[tid]; }
    if (tid == 0) s_b2 = b2[0];
    __syncthreads();

    const int idx = blockIdx.x * blockDim.x + tid;
    if (idx >= B_ * C_ * M_) return;
    const int m  = idx & (M_ - 1);
    const int bc = idx >> 7;          // b*C + c

    const float px = positions[bc * 2 + 0];
    const float py = positions[bc * 2 + 1];
    const float tx = target[m * 2 + 0];
    const float ty = target[m * 2 + 1];
    const float dx = px - tx, dy = py - ty;
    const float d2 = dx * dx + dy * dy;

    // sigma = 0.1, 0.2, 0.4 -> inv = 1/(2 sigma^2) = 50, 12.5, 3.125
    const float s0 = __expf(-d2 * 50.0f);
    const float s1 = __expf(-d2 * 12.5f);
    const float s2 = __expf(-d2 * 3.125f);

    float acc = s_b2;
#pragma unroll
    for (int j = 0; j < 32; ++j) {
        float h = fmaf(s0, s_w1[j],
                  fmaf(s1, s_w1[32 + j],
                  fmaf(s2, s_w1[64 + j], s_b1[j])));
        acc = fmaf(fmaxf(h, 0.0f), s_w2[j], acc);
    }
    wout[idx] = acc;
}

// ---------------- Kernel B: scale[b][m] = 1/(sum_c w + 1e-8) ------------------
__global__ void sum_kernel(const float* __restrict__ w,    // [B,C,M]
                           float* __restrict__ scale) {    // [B,M]
    const int b = blockIdx.x;
    const int tid = threadIdx.x;          // 256
    const int m = tid & (M_ - 1);
    const int h = tid >> 7;               // 0 or 1
    const float* wb = w + b * C_ * M_;
    float s = 0.0f;
    for (int c = h; c < C_; c += 2) s += wb[c * M_ + m];
    __shared__ float sh[256];
    sh[tid] = s;
    __syncthreads();
    if (tid < M_) scale[b * M_ + tid] = 1.0f / (sh[tid] + sh[tid + M_] + 1e-8f);
}

// ---------------- Kernel C: out[b][m][t] = scale[b][m] * sum_c w[b][c][m] x[b][c][t]
// fp32 tiled GEMM: per-block tile 64 (m) x 128 (t), BK=16, 256 threads, 4x8 acc.
__global__ __launch_bounds__(256)
void merge_gemm(const float* __restrict__ x,      // [B,C,T]
                const float* __restrict__ w,      // [B,C,M]
                const float* __restrict__ scale,  // [B,M]
                float* __restrict__ out) {        // [B,M,T]
    const int t0 = blockIdx.x * 128;
    const int m0 = blockIdx.y * 64;
    const int b  = blockIdx.z;
    const int tid = threadIdx.x;

    __shared__ float xs[16][132];   // +4 pad
    __shared__ float wsm[16][68];   // +4 pad

    const float* xb = x + (size_t)b * C_ * T_;
    const float* wb = w + (size_t)b * C_ * M_;

    float acc[4][8];
#pragma unroll
    for (int i = 0; i < 4; ++i)
#pragma unroll
        for (int j = 0; j < 8; ++j) acc[i][j] = 0.0f;

    const int tcol = tid & 15;   // t group: 8 floats each
    const int trow = tid >> 4;   // m group: 4 floats each

    for (int c0 = 0; c0 < C_; c0 += 16) {
        // stage x tile: 16 x 128 floats = 512 float4, 2 per thread
#pragma unroll
        for (int i = 0; i < 2; ++i) {
            const int l = tid + 256 * i;
            const int k = l >> 5;
            const int tq = (l & 31) * 4;
            const int c = c0 + k;
            const int t = t0 + tq;
            float4 v = make_float4(0.f, 0.f, 0.f, 0.f);
            if (c < C_ && t < T_) v = *(const float4*)(xb + (size_t)c * T_ + t);
            *(float4*)(&xs[k][tq]) = v;
        }
        // stage w tile: 16 x 64 floats = 256 float4, 1 per thread
        {
            const int k = tid >> 4;
            const int mq = (tid & 15) * 4;
            const int c = c0 + k;
            float4 v = make_float4(0.f, 0.f, 0.f, 0.f);
            if (c < C_) v = *(const float4*)(wb + (size_t)c * M_ + m0 + mq);
            *(float4*)(&wsm[k][mq]) = v;
        }
        __syncthreads();

#pragma unroll
        for (int k = 0; k < 16; ++k) {
            float wf[4], xf[8];
            *(float4*)wf       = *(const float4*)(&wsm[k][trow * 4]);
            *(float4*)(xf)     = *(const float4*)(&xs[k][tcol * 8]);
            *(float4*)(xf + 4) = *(const float4*)(&xs[k][tcol * 8 + 4]);
#pragma unroll
            for (int i = 0; i < 4; ++i)
#pragma unroll
                for (int j = 0; j < 8; ++j)
                    acc[i][j] = fmaf(wf[i], xf[j], acc[i][j]);
        }
        __syncthreads();
    }

    // epilogue: fold channel-normalization scale, store float4
#pragma unroll
    for (int i = 0; i < 4; ++i) {
        const int m = m0 + trow * 4 + i;
        const float sc = scale[b * M_ + m];
        float* op = out + ((size_t)b * M_ + m) * T_;
#pragma unroll
        for (int j0 = 0; j0 < 8; j0 += 4) {
            const int t = t0 + tcol * 8 + j0;
            if (t < T_) {
                float4 v = make_float4(acc[i][j0] * sc, acc[i][j0 + 1] * sc,
                                       acc[i][j0 + 2] * sc, acc[i][j0 + 3] * sc);
                *(float4*)(op + t) = v;
            }
        }
    }
}

extern "C" void kernel_launch(void* const* d_in, const int* in_sizes, int n_in,
                              void* d_out, int out_size, void* d_ws, size_t ws_size,
                              hipStream_t stream) {
    const float* x         = (const float*)d_in[0];
    const float* positions = (const float*)d_in[1];
    const float* target    = (const float*)d_in[2];
    const float* w1        = (const float*)d_in[3];
    const float* b1        = (const float*)d_in[4];
    const float* w2        = (const float*)d_in[5];
    const float* b2        = (const float*)d_in[6];
    float* out = (float*)d_out;

    float* wbuf  = (float*)d_ws;            // B*C*M floats = 2.51 MB
    float* scale = wbuf + B_ * C_ * M_;     // B*M floats

    gate_kernel<<<(B_ * C_ * M_) / 256, 256, 0, stream>>>(positions, target,
                                                          w1, b1, w2, b2, wbuf);
    sum_kernel<<<B_, 256, 0, stream>>>(wbuf, scale);

    dim3 grid((T_ + 127) / 128, M_ / 64, B_);
    merge_gemm<<<grid, 256, 0, stream>>>(x, wbuf, scale, out);
}

// Round 2
// 150.026 us; speedup vs baseline: 1.5126x; 1.5126x over previous
//
#include <hip/hip_runtime.h>

#define B_ 16
#define C_ 306
#define CP_ 320
#define T_ 4000
#define M_ 128

typedef short bf16x8 __attribute__((ext_vector_type(8)));
typedef float f32x4 __attribute__((ext_vector_type(4)));

// ---------- Kernel A: gate MLP -> w_hi/w_lo [B][M][CP_] bf16 + scale[B][M] ----
// one block per (b, m); 320 threads (c = tid); also computes 1/(sum_c w + 1e-8)
__global__ __launch_bounds__(320)
void gate_kernel(const float* __restrict__ positions,   // [B,C,2]
                 const float* __restrict__ target,      // [M,2]
                 const float* __restrict__ w1,          // [3,32]
                 const float* __restrict__ b1,          // [32]
                 const float* __restrict__ w2,          // [32]
                 const float* __restrict__ b2,          // [1]
                 unsigned short* __restrict__ w_hi,     // [B,M,CP_]
                 unsigned short* __restrict__ w_lo,     // [B,M,CP_]
                 float* __restrict__ scale) {           // [B,M]
    const int bm = blockIdx.x;
    const int b = bm >> 7;
    const int m = bm & (M_ - 1);
    const int tid = threadIdx.x;   // 0..319

    __shared__ float s_w1[96], s_b1[32], s_w2[32];
    __shared__ float s_b2, s_tx, s_ty;
    __shared__ float s_part[5];

    if (tid < 96) s_w1[tid] = w1[tid];
    if (tid < 32) { s_b1[tid] = b1[tid]; s_w2[tid] = w2[tid]; }
    if (tid == 256) s_b2 = b2[0];
    if (tid == 257) s_tx = target[m * 2 + 0];
    if (tid == 258) s_ty = target[m * 2 + 1];
    __syncthreads();

    float w = 0.0f;
    if (tid < C_) {
        const float px = positions[(b * C_ + tid) * 2 + 0];
        const float py = positions[(b * C_ + tid) * 2 + 1];
        const float dx = px - s_tx, dy = py - s_ty;
        const float d2 = dx * dx + dy * dy;
        const float s0 = __expf(-d2 * 50.0f);
        const float s1 = __expf(-d2 * 12.5f);
        const float s2 = __expf(-d2 * 3.125f);
        float acc = s_b2;
#pragma unroll
        for (int j = 0; j < 32; ++j) {
            float h = fmaf(s0, s_w1[j],
                      fmaf(s1, s_w1[32 + j],
                      fmaf(s2, s_w1[64 + j], s_b1[j])));
            acc = fmaf(fmaxf(h, 0.0f), s_w2[j], acc);
        }
        w = acc;
    }

    // block-wide sum of w
    float s = w;
#pragma unroll
    for (int off = 32; off > 0; off >>= 1) s += __shfl_down(s, off, 64);
    if ((tid & 63) == 0) s_part[tid >> 6] = s;
    __syncthreads();
    if (tid == 0) {
        float tot = s_part[0] + s_part[1] + s_part[2] + s_part[3] + s_part[4];
        scale[bm] = 1.0f / (tot + 1e-8f);
    }

    // split w into bf16 hi (truncate) + lo
    const unsigned int u = __float_as_uint(w);
    const unsigned short h = (unsigned short)(u >> 16);
    const float lof = w - __uint_as_float(u & 0xffff0000u);
    const unsigned short l = (unsigned short)(__float_as_uint(lof) >> 16);
    w_hi[(size_t)bm * CP_ + tid] = h;
    w_lo[(size_t)bm * CP_ + tid] = l;
}

// ---------- Kernel B: MFMA GEMM  out[b][m][t] = scale[b][m] * sum_c w*x ------
// block tile: m = 128 (all), t = 128; 4 waves of 64x64; BK = 32; 3-pass split bf16
__global__ __launch_bounds__(256, 2)
void merge_gemm(const float* __restrict__ x,            // [B,C,T]
                const unsigned short* __restrict__ w_hi,// [B,M,CP_]
                const unsigned short* __restrict__ w_lo,
                const float* __restrict__ scale,        // [B,M]
                float* __restrict__ out) {              // [B,M,T]
    const int t0 = blockIdx.x * 128;
    const int b  = blockIdx.y;
    const int tid  = threadIdx.x;
    const int lane = tid & 63;
    const int wv   = tid >> 6;
    const int tquad = lane >> 4;   // 0..3
    const int tsub  = lane & 15;   // 0..15

    // LDS: runs of 8 halfs: [r (0..3)][row (0..127)][8]
    __shared__ __align__(16) unsigned short sWh[4096];
    __shared__ __align__(16) unsigned short sWl[4096];
    __shared__ __align__(16) unsigned short sXh[4096];
    __shared__ __align__(16) unsigned short sXl[4096];
    __shared__ __align__(16) float sScale[M_];

    if (tid < M_) sScale[tid] = scale[b * M_ + tid];

    const float* xb = x + (size_t)b * C_ * T_;
    const unsigned short* whB = w_hi + (size_t)b * M_ * CP_;
    const unsigned short* wlB = w_lo + (size_t)b * M_ * CP_;

    f32x4 acc[4][4];
#pragma unroll
    for (int i = 0; i < 4; ++i)
#pragma unroll
        for (int j = 0; j < 4; ++j) acc[i][j] = (f32x4){0.f, 0.f, 0.f, 0.f};

    const int mw = (wv & 1) * 64;    // wave m-origin
    const int tw = (wv >> 1) * 64;   // wave t-origin

    for (int step = 0; step < CP_ / 32; ++step) {
        const int c0 = step * 32;

        // ---- stage W tile: [4 r][128 m][8] hi+lo (pre-split bf16, contiguous)
#pragma unroll
        for (int pp = 0; pp < 2; ++pp) {
            const int idx = tid + 256 * pp;      // 0..511
            const int mm = idx >> 2;
            const int r  = idx & 3;
            const size_t goff = (size_t)mm * CP_ + c0 + r * 8;
            *(uint4*)(sWh + (r * 128 + mm) * 8) = *(const uint4*)(whB + goff);
            *(uint4*)(sWl + (r * 128 + mm) * 8) = *(const uint4*)(wlB + goff);
        }

        // ---- stage X tile transposed: [4 r][128 t][8], split fp32 -> hi/lo
#pragma unroll
        for (int s = 0; s < 2; ++s) {
            const int t = wv * 16 + tsub + s * 64;          // 0..127
            const int tg = min(t0 + t, T_ - 1);
            const float* xcol = xb + tg;
#pragma unroll
            for (int k = 0; k < 4; ++k) {
                const int p = tquad + 4 * k;                // c-pair 0..15
                const int c = c0 + 2 * p;
                const int ca = min(c, C_ - 1);
                const int cb = min(c + 1, C_ - 1);
                const float xa = xcol[(size_t)ca * T_];
                const float xv = xcol[(size_t)cb * T_];
                const unsigned int ua = __float_as_uint(xa);
                const unsigned int ub = __float_as_uint(xv);
                const unsigned int hp = (ua >> 16) | (ub & 0xffff0000u);
                const float la = xa - __uint_as_float(ua & 0xffff0000u);
                const float lb = xv - __uint_as_float(ub & 0xffff0000u);
                const unsigned int lp = (__float_as_uint(la) >> 16) |
                                        (__float_as_uint(lb) & 0xffff0000u);
                const int off32 = (p >> 2) * 512 + t * 4 + (p & 3);
                ((unsigned int*)sXh)[off32] = hp;
                ((unsigned int*)sXl)[off32] = lp;
            }
        }
        __syncthreads();

        // ---- fragments + MFMA
        bf16x8 ah[4], al[4], bh[4], bl[4];
#pragma unroll
        for (int i = 0; i < 4; ++i) {
            const int moff = tquad * 1024 + (mw + i * 16 + tsub) * 8;
            ah[i] = *(const bf16x8*)(sWh + moff);
            al[i] = *(const bf16x8*)(sWl + moff);
            const int toff = tquad * 1024 + (tw + i * 16 + tsub) * 8;
            bh[i] = *(const bf16x8*)(sXh + toff);
            bl[i] = *(const bf16x8*)(sXl + toff);
        }
#pragma unroll
        for (int mi = 0; mi < 4; ++mi)
#pragma unroll
            for (int ti = 0; ti < 4; ++ti) {
                acc[mi][ti] = __builtin_amdgcn_mfma_f32_16x16x32_bf16(
                    ah[mi], bh[ti], acc[mi][ti], 0, 0, 0);
                acc[mi][ti] = __builtin_amdgcn_mfma_f32_16x16x32_bf16(
                    ah[mi], bl[ti], acc[mi][ti], 0, 0, 0);
                acc[mi][ti] = __builtin_amdgcn_mfma_f32_16x16x32_bf16(
                    al[mi], bh[ti], acc[mi][ti], 0, 0, 0);
            }
        __syncthreads();
    }

    // ---- epilogue: fold scale, store (C/D: col = lane&15, row = quad*4+reg)
#pragma unroll
    for (int mi = 0; mi < 4; ++mi) {
        const int mbase = mw + mi * 16 + tquad * 4;
        const float4 sc = *(const float4*)(sScale + mbase);
#pragma unroll
        for (int ti = 0; ti < 4; ++ti) {
            const int tg = t0 + tw + ti * 16 + tsub;
            if (tg < T_) {
                float* op = out + ((size_t)b * M_ + mbase) * T_ + tg;
                op[0 * T_] = acc[mi][ti][0] * sc.x;
                op[1 * T_] = acc[mi][ti][1] * sc.y;
                op[2 * T_] = acc[mi][ti][2] * sc.z;
                op[3 * T_] = acc[mi][ti][3] * sc.w;
            }
        }
    }
}

extern "C" void kernel_launch(void* const* d_in, const int* in_sizes, int n_in,
                              void* d_out, int out_size, void* d_ws, size_t ws_size,
                              hipStream_t stream) {
    const float* x         = (const float*)d_in[0];
    const float* positions = (const float*)d_in[1];
    const float* target    = (const float*)d_in[2];
    const float* w1        = (const float*)d_in[3];
    const float* b1        = (const float*)d_in[4];
    const float* w2        = (const float*)d_in[5];
    const float* b2        = (const float*)d_in[6];
    float* out = (float*)d_out;

    unsigned short* w_hi = (unsigned short*)d_ws;                 // B*M*CP halfs
    unsigned short* w_lo = w_hi + (size_t)B_ * M_ * CP_;
    float* scale = (float*)(w_lo + (size_t)B_ * M_ * CP_);        // B*M floats

    gate_kernel<<<B_ * M_, 320, 0, stream>>>(positions, target, w1, b1, w2, b2,
                                             w_hi, w_lo, scale);

    dim3 grid((T_ + 127) / 128, B_);
    merge_gemm<<<grid, 256, 0, stream>>>(x, w_hi, w_lo, scale, out);
}